// Round 8
// baseline (207.665 us; speedup 1.0000x reference)
//
#include <hip/hip_runtime.h>

// ---------- types ----------
typedef __attribute__((ext_vector_type(4))) float  f32x4;
typedef __attribute__((ext_vector_type(8))) short  s16x8;   // 8 bf16 (4 VGPRs)
typedef __attribute__((ext_vector_type(8))) unsigned short u16x8;
typedef __attribute__((ext_vector_type(4))) unsigned short u16x4;

static __device__ __forceinline__ unsigned short f2bf(float f) {
    unsigned int u = __builtin_bit_cast(unsigned int, f);
    u += 0x7fffu + ((u >> 16) & 1u);      // round-to-nearest-even
    return (unsigned short)(u >> 16);
}

static __device__ __forceinline__ unsigned int cvt_pk_bf16(float lo, float hi) {
    unsigned int r;
    asm("v_cvt_pk_bf16_f32 %0, %1, %2" : "=v"(r) : "v"(lo), "v"(hi));
    return r;
}

static __device__ __forceinline__ void gload16(const void* g, void* l) {
    __builtin_amdgcn_global_load_lds(
        (const __attribute__((address_space(1))) void*)g,
        (__attribute__((address_space(3))) void*)l, 16, 0, 0);
}

#define MFMA16(MB)                                                          \
    _Pragma("unroll")                                                       \
    for (int mi = 0; mi < 4; ++mi) {                                        \
        _Pragma("unroll")                                                   \
        for (int ni = 0; ni < 4; ++ni)                                      \
            acc[(MB) + mi][ni] = __builtin_amdgcn_mfma_f32_16x16x32_bf16(   \
                af[mi], bf[ni], acc[(MB) + mi][ni], 0, 0, 0);               \
    }

// =====================================================================
// fp32 -> bf16 convert pass: q,k,v + 4 weights. 2048 elems/block.
// =====================================================================
__global__ __launch_bounds__(256)
void conv_kernel(const float* __restrict__ q, const float* __restrict__ k,
                 const float* __restrict__ v,
                 const float* __restrict__ wq, const float* __restrict__ wk,
                 const float* __restrict__ wv, const float* __restrict__ wo,
                 unsigned short* __restrict__ qb, unsigned short* __restrict__ kb,
                 unsigned short* __restrict__ vb, unsigned short* __restrict__ wb)
{
    const int bid = blockIdx.x;
    const float* src; unsigned short* dst; int inner;
    if      (bid < 4096)  { src = q;  dst = qb; inner = bid; }
    else if (bid < 8192)  { src = k;  dst = kb; inner = bid - 4096; }
    else if (bid < 12288) { src = v;  dst = vb; inner = bid - 8192; }
    else {
        const int wseg = (bid - 12288) >> 9;
        src = wseg == 0 ? wq : wseg == 1 ? wk : wseg == 2 ? wv : wo;
        dst = wb + (size_t)wseg * 1048576;
        inner = (bid - 12288) & 511;
    }
    const size_t e0 = (size_t)inner * 2048 + threadIdx.x * 8;
    f32x4 a = *(const f32x4*)(src + e0);
    f32x4 b = *(const f32x4*)(src + e0 + 4);
    u16x8 o;
    #pragma unroll
    for (int i = 0; i < 4; ++i) { o[i] = f2bf(a[i]); o[i + 4] = f2bf(b[i]); }
    *(u16x8*)(dst + e0) = o;
}

// =====================================================================
// bf16 NT GEMM, m201 geometry: 256x256 tile, BK=64, 8 waves (2M x 4N,
// per-wave 128x64), double-buffered LDS (128 KB), 4 phases per K-step:
//   P1 {8 ds_read (B ks0 + A mi0-3 ks0); issue ALL 8 gload_lds(t+1);
//       bar; lgkm(0); 16 MFMA; bar}
//   P2 {4 ds_read (A mi4-7 ks0); bar; lgkm; 16 MFMA; bar}
//   P3 {8 ds_read (ks1); bar; lgkm; 16 MFMA; bar}
//   P4 {4 ds_read; bar; lgkm; 16 MFMA; vmcnt(0) <- t+1's loads, issued
//       3 phases ago; bar}   (buffer-ready gate BEFORE next P1's reads)
// EPI 0: fused QKV. grid 384 (3 seg x 32 by x 4 bx), XCD-swizzled.
//        seg0 -> Qh [B,H,L,64] * 0.125 ; seg1 -> Kh ; seg2 -> Vt [B,H,64,L]
// EPI 1: out proj. grid 128. Of fp32 [8192,1024].
// =====================================================================
template<int EPI>
__global__ __launch_bounds__(512, 2)
void gemmW(const unsigned short* __restrict__ A0,
           const unsigned short* __restrict__ A1,
           const unsigned short* __restrict__ A2,
           const unsigned short* __restrict__ Bw,
           unsigned short* __restrict__ O0, unsigned short* __restrict__ O1,
           unsigned short* __restrict__ O2, float* __restrict__ Of)
{
    __shared__ unsigned short Asw[2][256 * 64];   // 64 KB
    __shared__ unsigned short Bsw[2][256 * 64];   // 64 KB

    const int tid  = threadIdx.x;
    const int lane = tid & 63;
    const int wave = tid >> 6;
    const int wr   = wave >> 2, wc = wave & 3;    // 2M x 4N waves, 128x64 each
    const int g    = lane >> 4, l16 = lane & 15;

    const int nblk = (EPI == 0) ? 384 : 128;
    const int cpx  = nblk >> 3;
    const int wg   = (blockIdx.x & 7) * cpx + (blockIdx.x >> 3);  // bijective XCD swizzle
    const int bx   = wg & 3;
    const int byt  = wg >> 2;
    const int seg  = byt >> 5;          // 0 for EPI 1 (byt < 32)
    const int byl  = byt & 31;

    const unsigned short* Ap = (EPI == 0) ? (seg == 0 ? A0 : seg == 1 ? A1 : A2) : A0;
    const unsigned short* Arow = Ap + (size_t)(byl * 256) * 1024;
    const unsigned short* Brow = Bw + (size_t)seg * 1048576 + (size_t)(bx * 256) * 1024;

    f32x4 acc[8][4] = {};

    // 16B staging chunk j (0..3): linear LDS dest, inverse-swizzled source.
    auto stageA = [&](int buf, int kt2, int j) {
        const int idx = j * 512 + tid;         // 0..2047 -> 256 rows x 8 chunks
        const int r   = idx >> 3;
        const int cl  = (tid & 7) ^ (r & 7);
        gload16(Arow + (size_t)r * 1024 + kt2 * 64 + cl * 8,
                (char*)Asw[buf] + j * 8192 + wave * 1024);
    };
    auto stageB = [&](int buf, int kt2, int j) {
        const int idx = j * 512 + tid;
        const int r   = idx >> 3;
        const int cl  = (tid & 7) ^ (r & 7);
        gload16(Brow + (size_t)r * 1024 + kt2 * 64 + cl * 8,
                (char*)Bsw[buf] + j * 8192 + wave * 1024);
    };
    auto lda = [&](const char* Ab, int mi, int ks) -> s16x8 {
        const int row = wr * 128 + mi * 16 + l16;
        const int off = (row * 128 + g * 16 + ks * 64) ^ ((row & 7) << 4);
        return __builtin_bit_cast(s16x8, *(const u16x8*)(Ab + off));
    };
    auto ldb = [&](const char* Bb, int ni, int ks) -> s16x8 {
        const int row = wc * 64 + ni * 16 + l16;
        const int off = (row * 128 + g * 16 + ks * 64) ^ ((row & 7) << 4);
        return __builtin_bit_cast(s16x8, *(const u16x8*)(Bb + off));
    };

    // prologue: stage K-step 0 into buf 0, drain, barrier.
    #pragma unroll
    for (int j = 0; j < 4; ++j) stageA(0, 0, j);
    #pragma unroll
    for (int j = 0; j < 4; ++j) stageB(0, 0, j);
    asm volatile("s_waitcnt vmcnt(0)" ::: "memory");
    __builtin_amdgcn_s_barrier();

    for (int t = 0; t < 16; ++t) {
        const int cur = t & 1;
        const char* Ab = (const char*)Asw[cur];
        const char* Bb = (const char*)Bsw[cur];
        s16x8 af[4], bf[4];

        // ---- P1: B(ks0) x4 + A(mi0-3, ks0); issue all 8 stages for t+1 ----
        #pragma unroll
        for (int ni = 0; ni < 4; ++ni) bf[ni] = ldb(Bb, ni, 0);
        #pragma unroll
        for (int mi = 0; mi < 4; ++mi) af[mi] = lda(Ab, mi, 0);
        if (t + 1 < 16) {
            const int nb = cur ^ 1;
            #pragma unroll
            for (int j = 0; j < 4; ++j) stageA(nb, t + 1, j);
            #pragma unroll
            for (int j = 0; j < 4; ++j) stageB(nb, t + 1, j);
        }
        __builtin_amdgcn_s_barrier();
        asm volatile("s_waitcnt lgkmcnt(0)" ::: "memory");
        __builtin_amdgcn_s_setprio(1);
        MFMA16(0)
        __builtin_amdgcn_s_setprio(0);
        __builtin_amdgcn_s_barrier();

        // ---- P2: A(mi4-7, ks0); reuse bf ----
        #pragma unroll
        for (int mi = 0; mi < 4; ++mi) af[mi] = lda(Ab, 4 + mi, 0);
        __builtin_amdgcn_s_barrier();
        asm volatile("s_waitcnt lgkmcnt(0)" ::: "memory");
        __builtin_amdgcn_s_setprio(1);
        MFMA16(4)
        __builtin_amdgcn_s_setprio(0);
        __builtin_amdgcn_s_barrier();

        // ---- P3: B(ks1) x4 + A(mi0-3, ks1) ----
        #pragma unroll
        for (int ni = 0; ni < 4; ++ni) bf[ni] = ldb(Bb, ni, 1);
        #pragma unroll
        for (int mi = 0; mi < 4; ++mi) af[mi] = lda(Ab, mi, 1);
        __builtin_amdgcn_s_barrier();
        asm volatile("s_waitcnt lgkmcnt(0)" ::: "memory");
        __builtin_amdgcn_s_setprio(1);
        MFMA16(0)
        __builtin_amdgcn_s_setprio(0);
        __builtin_amdgcn_s_barrier();

        // ---- P4: A(mi4-7, ks1); then gate next buffer (loads 3 phases old) ----
        #pragma unroll
        for (int mi = 0; mi < 4; ++mi) af[mi] = lda(Ab, 4 + mi, 1);
        __builtin_amdgcn_s_barrier();
        asm volatile("s_waitcnt lgkmcnt(0)" ::: "memory");
        __builtin_amdgcn_s_setprio(1);
        MFMA16(4)
        __builtin_amdgcn_s_setprio(0);
        asm volatile("s_waitcnt vmcnt(0)" ::: "memory");
        __builtin_amdgcn_s_barrier();
    }

    // ---- epilogue ----
    #pragma unroll
    for (int mi = 0; mi < 8; ++mi) {
        #pragma unroll
        for (int ni = 0; ni < 4; ++ni) {
            const int gr0 = byl * 256 + wr * 128 + mi * 16 + g * 4;     // M base
            const int gc  = bx * 256 + wc * 64 + ni * 16 + l16;         // N
            if (EPI == 0 && seg == 2) {
                const int b = gr0 >> 11, ll = gr0 & 2047;
                const int h = gc >> 6,  dh = gc & 63;
                u16x4 pk;
                #pragma unroll
                for (int rr = 0; rr < 4; ++rr) pk[rr] = f2bf(acc[mi][ni][rr]);
                *(u16x4*)(O2 + (size_t)((b * 16 + h) * 64 + dh) * 2048 + ll) = pk;
            } else {
                #pragma unroll
                for (int rr = 0; rr < 4; ++rr) {
                    const int gr = gr0 + rr;
                    float v = acc[mi][ni][rr];
                    if (EPI == 0) {
                        const int b = gr >> 11, ll = gr & 2047;
                        const int h = gc >> 6,  dh = gc & 63;
                        if (seg == 0) {
                            v *= 0.125f;
                            O0[(size_t)((b * 16 + h) * 2048 + ll) * 64 + dh] = f2bf(v);
                        } else {
                            O1[(size_t)((b * 16 + h) * 2048 + ll) * 64 + dh] = f2bf(v);
                        }
                    } else {
                        Of[(size_t)gr * 1024 + gc] = v;
                    }
                }
            }
        }
    }
}

// =====================================================================
// Fallback GEMM (fp32 inputs converted in-loop) — only used if ws too small.
// =====================================================================
template<int AM, int BM, int EPI>
__global__ __launch_bounds__(256)
void gemm_k(const void* __restrict__ A0, const void* __restrict__ A1,
            const void* __restrict__ A2,
            const void* __restrict__ B0, const void* __restrict__ B1,
            const void* __restrict__ B2,
            unsigned short* __restrict__ O0, unsigned short* __restrict__ O1,
            unsigned short* __restrict__ O2, float* __restrict__ Of)
{
    __shared__ unsigned short Asw[128 * 64];
    __shared__ unsigned short Bsw[128 * 64];

    const int tid  = threadIdx.x;
    const int lane = tid & 63;
    const int wave = tid >> 6;
    const int wr   = wave >> 1, wc = wave & 1;
    const int g    = lane >> 4, l16 = lane & 15;

    const int nper = (EPI == 0) ? 192 : 64;
    const int wg   = (blockIdx.x & 7) * nper + (blockIdx.x >> 3);
    const int bx   = wg & 7;
    const int by   = wg >> 3;
    const int seg  = (EPI == 0) ? (by >> 6) : 0;
    const int byl  = (EPI == 0) ? (by & 63) : by;

    const void* Ap = seg == 0 ? A0 : seg == 1 ? A1 : A2;
    const void* Bp = seg == 0 ? B0 : seg == 1 ? B1 : B2;

    f32x4 acc[4][4] = {};

    for (int kt = 0; kt < 16; ++kt) {
        __syncthreads();
        if (AM == 0) {
            #pragma unroll
            for (int j = 0; j < 4; ++j) {
                const int idx = j * 256 + tid;
                const int r   = idx >> 3;
                const int cl  = (tid & 7) ^ (r & 7);
                gload16((const unsigned short*)Ap + (size_t)(byl * 128 + r) * 1024 + kt * 64 + cl * 8,
                        (char*)Asw + j * 4096 + wave * 1024);
            }
        } else {
            #pragma unroll
            for (int j = 0; j < 4; ++j) {
                const int idx = j * 256 + tid;
                const int r = idx >> 3, c = tid & 7;
                const float* src = (const float*)Ap + (size_t)(byl * 128 + r) * 1024 + kt * 64 + c * 8;
                f32x4 a = *(const f32x4*)src;
                f32x4 b = *(const f32x4*)(src + 4);
                u16x8 w;
                #pragma unroll
                for (int i = 0; i < 4; ++i) { w[i] = f2bf(a[i]); w[i + 4] = f2bf(b[i]); }
                *(u16x8*)((char*)Asw + ((r * 128 + c * 16) ^ ((r & 7) << 4))) = w;
            }
        }
        if (BM == 0) {
            #pragma unroll
            for (int j = 0; j < 4; ++j) {
                const int idx = j * 256 + tid;
                const int r   = idx >> 3;
                const int cl  = (tid & 7) ^ (r & 7);
                gload16((const unsigned short*)Bp + (size_t)(bx * 128 + r) * 1024 + kt * 64 + cl * 8,
                        (char*)Bsw + j * 4096 + wave * 1024);
            }
        } else {
            #pragma unroll
            for (int j = 0; j < 4; ++j) {
                const int idx = j * 256 + tid;
                const int r = idx >> 3, c = tid & 7;
                const float* src = (const float*)Bp + (size_t)(bx * 128 + r) * 1024 + kt * 64 + c * 8;
                f32x4 a = *(const f32x4*)src;
                f32x4 b = *(const f32x4*)(src + 4);
                u16x8 w;
                #pragma unroll
                for (int i = 0; i < 4; ++i) { w[i] = f2bf(a[i]); w[i + 4] = f2bf(b[i]); }
                *(u16x8*)((char*)Bsw + ((r * 128 + c * 16) ^ ((r & 7) << 4))) = w;
            }
        }
        __syncthreads();

        #pragma unroll
        for (int ks = 0; ks < 2; ++ks) {
            s16x8 af[4], bf[4];
            #pragma unroll
            for (int mi = 0; mi < 4; ++mi) {
                const int row = wr * 64 + mi * 16 + l16;
                const int off = (row * 128 + g * 16 + ks * 64) ^ ((row & 7) << 4);
                af[mi] = __builtin_bit_cast(s16x8, *(const u16x8*)((const char*)Asw + off));
            }
            #pragma unroll
            for (int ni = 0; ni < 4; ++ni) {
                const int row = wc * 64 + ni * 16 + l16;
                const int off = (row * 128 + g * 16 + ks * 64) ^ ((row & 7) << 4);
                bf[ni] = __builtin_bit_cast(s16x8, *(const u16x8*)((const char*)Bsw + off));
            }
            #pragma unroll
            for (int mi = 0; mi < 4; ++mi)
                #pragma unroll
                for (int ni = 0; ni < 4; ++ni)
                    acc[mi][ni] = __builtin_amdgcn_mfma_f32_16x16x32_bf16(
                        af[mi], bf[ni], acc[mi][ni], 0, 0, 0);
        }
    }

    #pragma unroll
    for (int mi = 0; mi < 4; ++mi) {
        #pragma unroll
        for (int ni = 0; ni < 4; ++ni) {
            #pragma unroll
            for (int rr = 0; rr < 4; ++rr) {
                const int gr = byl * 128 + wr * 64 + mi * 16 + g * 4 + rr;
                const int gc = bx * 128 + wc * 64 + ni * 16 + l16;
                float v = acc[mi][ni][rr];
                if (EPI == 0) {
                    const int b = gr >> 11, ll = gr & 2047, h = gc >> 6, dh = gc & 63;
                    if (seg == 0) {
                        v *= 0.125f;
                        O0[(size_t)((b * 16 + h) * 2048 + ll) * 64 + dh] = f2bf(v);
                    } else if (seg == 1) {
                        O1[(size_t)((b * 16 + h) * 2048 + ll) * 64 + dh] = f2bf(v);
                    } else {
                        O2[(size_t)((b * 16 + h) * 64 + dh) * 2048 + ll] = f2bf(v);
                    }
                } else {
                    Of[(size_t)gr * 1024 + gc] = v;
                }
            }
        }
    }
}

// =====================================================================
// Flash-style causal attention (unchanged from R5/R6).
// =====================================================================
__global__ __launch_bounds__(512)
void attn_kernel(const unsigned short* __restrict__ Qh,
                 const unsigned short* __restrict__ Kh,
                 const unsigned short* __restrict__ Vt,
                 unsigned short* __restrict__ Ctx)
{
    __shared__ unsigned short Ksw[2][64 * 64];
    __shared__ unsigned short Vsw[2][64 * 64];
    __shared__ unsigned short Psw[8][16 * 64];

    const int tid  = threadIdx.x;
    const int lane = tid & 63;
    const int wave = tid >> 6;
    const int g    = lane >> 4, l16 = lane & 15;
    const int qb   = 15 - (int)(blockIdx.x >> 6);
    const int bh   = blockIdx.x & 63;
    const int b    = bh >> 4, h = bh & 15;
    const int qrow0 = qb * 128 + wave * 16;
    const int ntile = 2 * qb + 2;

    const int sr = tid >> 3, sc = tid & 7;
    const int soff = (sr * 128 + sc * 16) ^ ((sr & 7) << 4);
    const unsigned short* kbase = Kh + ((size_t)bh * 2048 + sr) * 64 + sc * 8;
    const unsigned short* vbase = Vt + ((size_t)bh * 64 + sr) * 2048 + sc * 8;

    s16x8 qf[2];
    {
        const unsigned short* qp = Qh + ((size_t)bh * 2048 + qrow0 + l16) * 64 + g * 8;
        qf[0] = __builtin_bit_cast(s16x8, *(const u16x8*)qp);
        qf[1] = __builtin_bit_cast(s16x8, *(const u16x8*)(qp + 32));
    }

    f32x4 o[4] = {};
    float m = -3.0e38f, l = 0.f;   // per-lane row state: q = l16

    *(u16x8*)((char*)Ksw[0] + soff) = *(const u16x8*)kbase;
    *(u16x8*)((char*)Vsw[0] + soff) = *(const u16x8*)vbase;
    __syncthreads();

    int cur = 0;
    for (int t = 0; t < ntile; ++t) {
        const int kv0 = t * 64;

        u16x8 kn, vn;
        const bool hn = (t + 1 < ntile);
        if (hn) {
            kn = *(const u16x8*)(kbase + (size_t)(kv0 + 64) * 64);
            vn = *(const u16x8*)(vbase + (kv0 + 64));
        }

        if (kv0 <= qrow0 + 15) {
            const char* Kb = (const char*)Ksw[cur];
            const char* Vb = (const char*)Vsw[cur];

            f32x4 st[4] = {};
            __builtin_amdgcn_s_setprio(1);
            #pragma unroll
            for (int nt = 0; nt < 4; ++nt) {
                #pragma unroll
                for (int ks = 0; ks < 2; ++ks) {
                    const int row = nt * 16 + l16;
                    const int off = (row * 128 + g * 16 + ks * 64) ^ ((row & 7) << 4);
                    s16x8 kf = __builtin_bit_cast(s16x8, *(const u16x8*)(Kb + off));
                    st[nt] = __builtin_amdgcn_mfma_f32_16x16x32_bf16(kf, qf[ks], st[nt], 0, 0, 0);
                }
            }
            __builtin_amdgcn_s_setprio(0);

            if (kv0 + 63 > qrow0) {
                const int q_g = qrow0 + l16;
                #pragma unroll
                for (int nt = 0; nt < 4; ++nt)
                    #pragma unroll
                    for (int rr = 0; rr < 4; ++rr) {
                        const int kv_g = kv0 + nt * 16 + g * 4 + rr;
                        if (kv_g > q_g) st[nt][rr] = -3.0e38f;
                    }
            }

            float pmax = fmaxf(
                fmaxf(fmaxf(fmaxf(st[0][0], st[0][1]), fmaxf(st[0][2], st[0][3])),
                      fmaxf(fmaxf(st[1][0], st[1][1]), fmaxf(st[1][2], st[1][3]))),
                fmaxf(fmaxf(fmaxf(st[2][0], st[2][1]), fmaxf(st[2][2], st[2][3])),
                      fmaxf(fmaxf(st[3][0], st[3][1]), fmaxf(st[3][2], st[3][3]))));
            pmax = fmaxf(pmax, __shfl_xor(pmax, 16));
            pmax = fmaxf(pmax, __shfl_xor(pmax, 32));

            if (__all(pmax <= m + 8.0f)) {
                float r0 = 0.f;
                #pragma unroll
                for (int nt = 0; nt < 4; ++nt)
                    #pragma unroll
                    for (int rr = 0; rr < 4; ++rr) {
                        const float p = __expf(st[nt][rr] - m);
                        st[nt][rr] = p;
                        r0 += p;
                    }
                r0 += __shfl_xor(r0, 16);
                r0 += __shfl_xor(r0, 32);
                l += r0;
            } else {
                const float mn = fmaxf(m, pmax);
                const float scf = __expf(m - mn);
                m = mn;
                float r0 = 0.f;
                #pragma unroll
                for (int nt = 0; nt < 4; ++nt)
                    #pragma unroll
                    for (int rr = 0; rr < 4; ++rr) {
                        const float p = __expf(st[nt][rr] - mn);
                        st[nt][rr] = p;
                        r0 += p;
                    }
                r0 += __shfl_xor(r0, 16);
                r0 += __shfl_xor(r0, 32);
                l = l * scf + r0;
                float sc4[4];
                #pragma unroll
                for (int rr = 0; rr < 4; ++rr) sc4[rr] = __shfl(scf, g * 4 + rr);
                #pragma unroll
                for (int nt = 0; nt < 4; ++nt)
                    #pragma unroll
                    for (int rr = 0; rr < 4; ++rr)
                        o[nt][rr] *= sc4[rr];
            }

            unsigned short* Pw = Psw[wave];
            #pragma unroll
            for (int nt = 0; nt < 4; ++nt) {
                const unsigned int w0 = cvt_pk_bf16(st[nt][0], st[nt][1]);
                const unsigned int w1 = cvt_pk_bf16(st[nt][2], st[nt][3]);
                const int off = (l16 * 128 + nt * 32 + g * 8) ^ ((l16 & 7) << 4);
                const unsigned long long dw = ((unsigned long long)w1 << 32) | w0;
                *(unsigned long long*)((char*)Pw + off) = dw;
            }

            __builtin_amdgcn_s_setprio(1);
            #pragma unroll
            for (int ks = 0; ks < 2; ++ks) {
                const int offp = (l16 * 128 + g * 16 + ks * 64) ^ ((l16 & 7) << 4);
                s16x8 pf = __builtin_bit_cast(s16x8, *(const u16x8*)((const char*)Pw + offp));
                #pragma unroll
                for (int nt = 0; nt < 4; ++nt) {
                    const int row = nt * 16 + l16;
                    const int off = (row * 128 + g * 16 + ks * 64) ^ ((row & 7) << 4);
                    s16x8 vf = __builtin_bit_cast(s16x8, *(const u16x8*)(Vb + off));
                    o[nt] = __builtin_amdgcn_mfma_f32_16x16x32_bf16(pf, vf, o[nt], 0, 0, 0);
                }
            }
            __builtin_amdgcn_s_setprio(0);
        }

        if (hn) {
            *(u16x8*)((char*)Ksw[cur ^ 1] + soff) = kn;
            *(u16x8*)((char*)Vsw[cur ^ 1] + soff) = vn;
        }
        __syncthreads();
        cur ^= 1;
    }

    #pragma unroll
    for (int rr = 0; rr < 4; ++rr) {
        const float lq = __shfl(l, g * 4 + rr);
        const float inv = 1.0f / lq;
        const int q_g = qrow0 + g * 4 + rr;
        #pragma unroll
        for (int nt = 0; nt < 4; ++nt) {
            const int d = nt * 16 + l16;
            Ctx[((size_t)b * 2048 + q_g) * 1024 + h * 64 + d] = f2bf(o[nt][rr] * inv);
        }
    }
}

// =====================================================================
extern "C" void kernel_launch(void* const* d_in, const int* in_sizes, int n_in,
                              void* d_out, int out_size, void* d_ws, size_t ws_size,
                              hipStream_t stream)
{
    const float* q  = (const float*)d_in[0];
    const float* k  = (const float*)d_in[1];
    const float* v  = (const float*)d_in[2];
    const float* Wq = (const float*)d_in[4];
    const float* Wk = (const float*)d_in[5];
    const float* Wv = (const float*)d_in[6];
    const float* Wo = (const float*)d_in[7];

    const size_t NE = (size_t)4 * 16 * 2048 * 64;
    const size_t WE = (size_t)1024 * 1024;
    unsigned short* Qh = (unsigned short*)d_ws;
    unsigned short* Kh = Qh + NE;
    unsigned short* Vt = Kh + NE;
    float* outp = (float*)d_out;
    dim3 blk(256);

    if (ws_size >= 6 * NE * 2 + 4 * WE * 2) {
        unsigned short* qb  = Vt + NE;
        unsigned short* kb  = qb + NE;
        unsigned short* vb  = kb + NE;
        unsigned short* wb  = vb + NE;
        unsigned short* Ctx = qb;
        conv_kernel<<<dim3(14336), blk, 0, stream>>>(q, k, v, Wq, Wk, Wv, Wo,
                                                     qb, kb, vb, wb);
        gemmW<0><<<dim3(384), dim3(512), 0, stream>>>(
            qb, kb, vb, wb, Qh, Kh, Vt, nullptr);
        attn_kernel<<<dim3(1024), dim3(512), 0, stream>>>(Qh, Kh, Vt, Ctx);
        gemmW<1><<<dim3(128), dim3(512), 0, stream>>>(
            Ctx, nullptr, nullptr, wb + 3 * WE, nullptr, nullptr, nullptr, outp);
    } else {
        unsigned short* Ctx = Vt + NE;
        gemm_k<1, 1, 0><<<dim3(1536), blk, 0, stream>>>(
            q, k, v, Wq, Wk, Wv, Qh, Kh, Vt, nullptr);
        attn_kernel<<<dim3(1024), dim3(512), 0, stream>>>(Qh, Kh, Vt, Ctx);
        gemm_k<0, 1, 1><<<dim3(512), blk, 0, stream>>>(
            Ctx, nullptr, nullptr, Wo, nullptr, nullptr,
            nullptr, nullptr, nullptr, outp);
    }
}